// Round 3
// baseline (68.485 us; speedup 1.0000x reference)
//
#include <hip/hip_runtime.h>
#include <hip/hip_bf16.h>

// TreeCnnLayer: y[b,l,o] = relu( sum_{k=0..3} x[b, idx[l,k], :] . mask[k,:,o] + bias[127] )
// == GEMM: A[131072 x 512] (gathered, fp32->bf16) * Bm[512 x 128] (mask), fp32 out.
//
// R2 changes (R1 was latency-bound: occ 17.7%, VGPR spill from 128-reg resident bfrag):
//  - B fragments prepped ONCE into a bf16 frag-layout __device__ buffer (128 KiB, L2-resident)
//    by a tiny prep kernel; main loop streams them as coalesced dwordx4 loads. Frees ~128 VGPR.
//  - grid 512 -> 1024 (4 blocks/CU), __launch_bounds__(256,4) -> 16 waves/CU.
//  - XCD-chunked block swizzle: each XCD owns a contiguous node range (gather L2 locality).

namespace {

constexpr int kNodes = 8192;        // n+1
constexpr int kIn = 128;
constexpr int kOut = 128;
constexpr int kRows = 32;           // rows per block-iter
constexpr int kThreads = 256;
constexpr int kGrid = 1024;
constexpr int kTotalIters = (16 * kNodes) / kRows;      // 4096
constexpr int kItersPerBlock = kTotalIters / kGrid;     // 4

typedef __attribute__((ext_vector_type(8))) short short8;   // 8 bf16 = 4 VGPR (MFMA A/B frag)
typedef __attribute__((ext_vector_type(4))) short short4v;  // 4 bf16 = ds_write_b64
typedef __attribute__((ext_vector_type(4))) float f32x4;    // acc frag / staging load

// bf16 B fragments: [kk(16)][colgrp(8)][lane(64)] of short8 = 128 KiB, written by prep kernel.
__device__ short8 g_bfrag[16 * 8 * 64];

__device__ __forceinline__ short f2bf(float f) {
  return __builtin_bit_cast(short, __float2bfloat16(f));  // RNE
}

__device__ __forceinline__ int lds_off(int row, int kbyte) {
  // [32 rows][1024 B] with 16B-slot XOR swizzle -> ds_read_b128 conflict-free (G4 / T2)
  return row * 1024 + (kbyte ^ ((row & 7) << 4));
}

// Prep: mask (4,128,128) fp32 -> bf16 frag layout.
// Entry t: kk=t>>9, g=(t>>6)&7, lane=t&63; elem e: mask[(kk*32+(lane>>4)*8+e)*128 + g*16 + (lane&15)]
__global__ void prep_bfrag(const float* __restrict__ mask) {
  const int t = blockIdx.x * blockDim.x + threadIdx.x;
  const int kk = t >> 9, g = (t >> 6) & 7, lane = t & 63;
  const int krow = kk * 32 + (lane >> 4) * 8;
  const int col = g * 16 + (lane & 15);
  short8 pk;
#pragma unroll
  for (int e = 0; e < 8; ++e) pk[e] = f2bf(mask[(krow + e) * kOut + col]);
  g_bfrag[t] = pk;
}

__global__ __launch_bounds__(kThreads, 4)
void tree_gemm(const float* __restrict__ x, const float* __restrict__ bias,
               const int* __restrict__ itab, float* __restrict__ y) {
  __shared__ __align__(16) unsigned char ldsA[kRows * 512 * 2];  // 32 KiB bf16 A tile

  const int tid  = threadIdx.x;
  const int lane = tid & 63;
  const int wv   = tid >> 6;   // wave 0..3
  const int l15  = lane & 15;
  const int l4   = lane >> 4;  // quarter-wave 0..3

  const float blast = bias[kOut - 1];  // reference adds bias[-1] scalar

  // B stream base: wave wv owns colgrps {2wv, 2wv+1}
  const short8* bf = g_bfrag + (wv * 2) * 64 + lane;

  // XCD-chunked swizzle: xcd = bid%8 gets contiguous chunk of 128 block slots
  const int sb = (blockIdx.x & 7) * (kGrid / 8) + (blockIdx.x >> 3);

  // staging geometry: chunk-row cr = row*4+chunk; 32 lanes cover one 512B fp32 chunk-row
  const int crBase = wv * 32 + (lane >> 5);  // +2*j, j=0..15
  const int fOff   = (lane & 31) * 4;        // float offset within chunk-row

  f32x4 st[16];  // prefetched gather data (statically indexed only)

  auto loadregs = [&](int iter) {
    const int bb    = iter >> 8;           // 256 iters per batch
    const int lbase = (iter & 255) * kRows;
    const float* xb = x + (size_t)bb * kNodes * kIn;
    const int* ib = itab + (size_t)lbase * 4;
#pragma unroll
    for (int j = 0; j < 16; ++j) {
      const int cr = crBase + j * 2;
      const int gi = ib[cr];
      st[j] = *reinterpret_cast<const f32x4*>(xb + (size_t)gi * kIn + fOff);
    }
  };

  auto writelds = [&]() {
#pragma unroll
    for (int j = 0; j < 16; ++j) {
      const int cr    = crBase + j * 2;
      const int row   = cr >> 2;
      const int chunk = cr & 3;
      const int kbyte = chunk * 256 + (lane & 31) * 8;
      short4v pk;
      pk[0] = f2bf(st[j][0]); pk[1] = f2bf(st[j][1]);
      pk[2] = f2bf(st[j][2]); pk[3] = f2bf(st[j][3]);
      *reinterpret_cast<short4v*>(ldsA + lds_off(row, kbyte)) = pk;
    }
  };

  loadregs(sb);  // prologue prefetch

  for (int i = 0; i < kItersPerBlock; ++i) {
    const int iter = sb + i * kGrid;

    __syncthreads();   // previous compute done reading LDS
    writelds();        // cvt + ds_write current tile
    __syncthreads();   // LDS ready
    if (i + 1 < kItersPerBlock) loadregs(sb + (i + 1) * kGrid);  // fly under MFMAs

    f32x4 acc[2][2] = {};  // [rowtile][coltile]
#pragma unroll
    for (int kk = 0; kk < 16; ++kk) {
      const int kbyte = kk * 64 + l4 * 16;  // k_local=(kk*32 + l4*8) in bytes
      const short8 b0 = bf[kk * 512];       // colgrp 2wv,   L2-resident stream
      const short8 b1 = bf[kk * 512 + 64];  // colgrp 2wv+1
#pragma unroll
      for (int rt = 0; rt < 2; ++rt) {
        const int row = rt * 16 + l15;
        const short8 a =
            *reinterpret_cast<const short8*>(ldsA + lds_off(row, kbyte));
        acc[rt][0] = __builtin_amdgcn_mfma_f32_16x16x32_bf16(a, b0, acc[rt][0], 0, 0, 0);
        acc[rt][1] = __builtin_amdgcn_mfma_f32_16x16x32_bf16(a, b1, acc[rt][1], 0, 0, 0);
      }
    }

    // epilogue: D frag layout col=lane&15, row=(lane>>4)*4+r (m89-verified)
    const int bb    = iter >> 8;
    const int lbase = (iter & 255) * kRows;
    float* yb = y + ((size_t)bb * kNodes + lbase) * kOut;
    const int ocol = wv * 32 + l15;
#pragma unroll
    for (int rt = 0; rt < 2; ++rt) {
#pragma unroll
      for (int ct = 0; ct < 2; ++ct) {
#pragma unroll
        for (int r = 0; r < 4; ++r) {
          float v = acc[rt][ct][r] + blast;
          yb[(rt * 16 + l4 * 4 + r) * kOut + ocol + ct * 16] = v > 0.f ? v : 0.f;
        }
      }
    }
  }
}

}  // namespace

extern "C" void kernel_launch(void* const* d_in, const int* in_sizes, int n_in,
                              void* d_out, int out_size, void* d_ws, size_t ws_size,
                              hipStream_t stream) {
  const float* x    = (const float*)d_in[0];
  const float* mask = (const float*)d_in[1];
  const float* bias = (const float*)d_in[2];
  const int*   itab = (const int*)d_in[3];
  float*       y    = (float*)d_out;
  (void)in_sizes; (void)n_in; (void)out_size; (void)d_ws; (void)ws_size;

  prep_bfrag<<<dim3(32), dim3(256), 0, stream>>>(mask);
  tree_gemm<<<dim3(kGrid), dim3(kThreads), 0, stream>>>(x, bias, itab, y);
}

// Round 4
// 49.663 us; speedup vs baseline: 1.3790x; 1.3790x over previous
//
#include <hip/hip_runtime.h>
#include <hip/hip_bf16.h>

// TreeCnnLayer: y[b,l,o] = relu( sum_{k=0..3} x[b, idx[l,k], :] . mask[k,:,o] + bias[127] )
// == GEMM: A[131072 x 512] (gathered, fp32->bf16) * Bm[512 x 128] (mask), fp32 out.
//
// R4: R3's reg-staged gather spilled (VGPR_Count=64, +56MB scratch writes). Replace with
// async global_load_lds (width=16) staging fp32 straight to LDS:
//  - per-lane SOURCE addr carries gather + inverse XOR swizzle; LDS dest linear (rule #21)
//  - 16-row x K512 fp32 tiles, double-buffered 2x32KiB; 2-phase loop (T3 minimum)
//  - A-frag: 2x ds_read_b128 fp32 (swizzled, conflict-free) + cvt-on-read to bf16
//  - B fragments in VGPRs (128 regs) - occupancy is LDS-capped anyway, kills L2 B-stream
//  - grid 512 = 2 blocks/CU, all resident; contiguous 256-row chunk/block; XCD swizzle

namespace {

constexpr int kNodes = 8192;        // n+1
constexpr int kIn = 128;
constexpr int kOut = 128;
constexpr int kRowsPerTile = 16;
constexpr int kThreads = 256;
constexpr int kGrid = 512;
constexpr int kTilesPerBlock = 16;  // 256 rows per block; 512*256 = 131072 rows total

typedef __attribute__((ext_vector_type(8))) short short8;   // 8 bf16 (MFMA A/B frag)
typedef __attribute__((ext_vector_type(4))) float f32x4;

// bf16 B fragments: [kk(16)][colgrp(8)][lane(64)] of short8 = 128 KiB (L2-resident).
__device__ short8 g_bfrag[16 * 8 * 64];

__device__ __forceinline__ short f2bf(float f) {
  return __builtin_bit_cast(short, __float2bfloat16(f));  // RNE; fuses to v_cvt_pk_bf16_f32
}

// Prep: mask (4,128,128) fp32 -> bf16 MFMA-frag layout (proven in R2/R3).
__global__ void prep_bfrag(const float* __restrict__ mask) {
  const int t = blockIdx.x * blockDim.x + threadIdx.x;
  const int kk = t >> 9, g = (t >> 6) & 7, lane = t & 63;
  const int krow = kk * 32 + (lane >> 4) * 8;
  const int col = g * 16 + (lane & 15);
  short8 pk;
#pragma unroll
  for (int e = 0; e < 8; ++e) pk[e] = f2bf(mask[(krow + e) * kOut + col]);
  g_bfrag[t] = pk;
}

__global__ __launch_bounds__(kThreads, 2)
void tree_gemm(const float* __restrict__ x, const float* __restrict__ bias,
               const int* __restrict__ itab, float* __restrict__ y) {
  // 2 buffers x 16 rows x 512 fp32 (2048 B/row = 128 x 16B slots) = 64 KiB
  __shared__ __align__(16) float ldsA[2][kRowsPerTile * 512];

  const int tid  = threadIdx.x;
  const int lane = tid & 63;
  const int wv   = tid >> 6;   // wave 0..3
  const int l15  = lane & 15;
  const int l4   = lane >> 4;  // 0..3
  const int lh   = lane >> 5;  // 0..1 (neighbor select within stage pair)
  const int l31  = lane & 31;

  const float blast = bias[kOut - 1];

  // ---- B fragments resident in VGPRs: wave wv owns colgrps {2wv, 2wv+1} ----
  short8 bfA[16], bfB[16];
  {
    const short8* gb = g_bfrag + wv * 2 * 64 + lane;
#pragma unroll
    for (int kk = 0; kk < 16; ++kk) {
      bfA[kk] = gb[kk * 512];
      bfB[kk] = gb[kk * 512 + 64];
    }
  }

  // XCD-chunked bijective swizzle (512 % 8 == 0)
  const int sb = (blockIdx.x & 7) * (kGrid / 8) + (blockIdx.x >> 3);
  const int bb = sb >> 5;                                  // batch 0..15
  const int blockRow0 = (sb & 31) * (kRowsPerTile * kTilesPerBlock);  // node base
  const float* xb = x + (size_t)bb * kNodes * kIn;

  // Stage tile t into buffer bufsel. inst m (=wv*8+j): row r=m>>1, half h=m&1.
  // LDS linear: byte m*1024 + lane*16. Source pre-swizzled: lane L -> content slot
  // (L&31)^(r&7) of neighbor h*2+(L>>5). Read side XORs the same (r&7) back.
  auto stage = [&](int t, int bufsel) {
    const int lbase = blockRow0 + t * kRowsPerTile;
#pragma unroll
    for (int j = 0; j < 8; ++j) {
      const int m = wv * 8 + j;
      const int r = m >> 1, h = m & 1;
      const int2 gp = *reinterpret_cast<const int2*>(&itab[(lbase + r) * 4 + h * 2]);
      const int gi = lh ? gp.y : gp.x;
      const float* src = xb + (size_t)gi * kIn + ((l31 ^ (r & 7)) << 2);
      float* dst = &ldsA[bufsel][m * 256];  // wave-uniform base; HW adds lane*16
      __builtin_amdgcn_global_load_lds(
          (const __attribute__((address_space(1))) void*)src,
          (__attribute__((address_space(3))) void*)dst, 16, 0, 0);
    }
  };

  stage(0, 0);
  __syncthreads();  // drains vmcnt(0): tile 0 landed

  for (int t = 0; t < kTilesPerBlock; ++t) {
    const int cur = t & 1;
    if (t + 1 < kTilesPerBlock) stage(t + 1, cur ^ 1);  // async, flies under compute

    const float* buf = ldsA[cur];
    f32x4 acc0 = {}, acc1 = {};
#pragma unroll
    for (int kk = 0; kk < 16; ++kk) {
      // content slots kk*8 + l4*2 + {0,1}; stored at slot ^ (row&7)
      const int s0 = kk * 8 + ((l4 * 2) ^ (l15 & 7));
      const int s1 = kk * 8 + ((l4 * 2 + 1) ^ (l15 & 7));
      const f32x4 lo = *reinterpret_cast<const f32x4*>(buf + l15 * 512 + s0 * 4);
      const f32x4 hi = *reinterpret_cast<const f32x4*>(buf + l15 * 512 + s1 * 4);
      short8 a;
      a[0] = f2bf(lo[0]); a[1] = f2bf(lo[1]); a[2] = f2bf(lo[2]); a[3] = f2bf(lo[3]);
      a[4] = f2bf(hi[0]); a[5] = f2bf(hi[1]); a[6] = f2bf(hi[2]); a[7] = f2bf(hi[3]);
      acc0 = __builtin_amdgcn_mfma_f32_16x16x32_bf16(a, bfA[kk], acc0, 0, 0, 0);
      acc1 = __builtin_amdgcn_mfma_f32_16x16x32_bf16(a, bfB[kk], acc1, 0, 0, 0);
    }

    // epilogue: D frag col=lane&15, row=(lane>>4)*4+r (m89-verified)
    const int lbase = blockRow0 + t * kRowsPerTile;
    float* yb = y + ((size_t)bb * kNodes + lbase) * kOut;
    const int oc = wv * 32 + l15;
#pragma unroll
    for (int r = 0; r < 4; ++r) {
      const float v0 = acc0[r] + blast;
      const float v1 = acc1[r] + blast;
      yb[(l4 * 4 + r) * kOut + oc]      = v0 > 0.f ? v0 : 0.f;
      yb[(l4 * 4 + r) * kOut + oc + 16] = v1 > 0.f ? v1 : 0.f;
    }

    __syncthreads();  // all LDS reads of tile t done; also drains stage(t+1) loads
  }
}

}  // namespace

extern "C" void kernel_launch(void* const* d_in, const int* in_sizes, int n_in,
                              void* d_out, int out_size, void* d_ws, size_t ws_size,
                              hipStream_t stream) {
  const float* x    = (const float*)d_in[0];
  const float* mask = (const float*)d_in[1];
  const float* bias = (const float*)d_in[2];
  const int*   itab = (const int*)d_in[3];
  float*       y    = (float*)d_out;
  (void)in_sizes; (void)n_in; (void)out_size; (void)d_ws; (void)ws_size;

  prep_bfrag<<<dim3(32), dim3(256), 0, stream>>>(mask);
  tree_gemm<<<dim3(kGrid), dim3(kThreads), 0, stream>>>(x, bias, itab, y);
}